// Round 10
// baseline (207.925 us; speedup 1.0000x reference)
//
#include <hip/hip_runtime.h>
#include <cstdint>

#define R_SPHEREf 3.0f
#define NEARf 0.0f
#define FARf 100.0f
#define SECANT_STEPS 4
#define EPSf 1e-4f
#define R0f 1.0f
#define Hh 64
#define Lc 4
#define Sn 64

// tanh via: w2*tanh(x) = w2 + z/(1+exp2(C*x)),  z = -2*w2, C = 2*log2(e).
#define C_HI 2.88539004325866699f   // float-nearest 2*log2(e)
#define C_LO 3.8519227871e-08f      // residual for fma correction

typedef unsigned long long u64;

// x/y via v_rcp_f32 + 1 Newton step
__device__ __forceinline__ float fastdiv(float a, float b) {
    float rcp = __builtin_amdgcn_rcpf(b);
    rcp = __builtin_fmaf(rcp, __builtin_fmaf(-b, rcp, 1.0f), rcp);
    return a * rcp;
}

// (256, 8): cap VGPR at 64 -> 8 waves/SIMD. Safe ONLY together with the
// secant LDS-re-read diet below: r8 proved forcing this bound while the
// epilogue caches 24-32 fragment regs spills catastrophically (230/444 MB
// scratch traffic). Tripwire: FETCH/WRITE_SIZE must stay ~1 MB.
__global__ __launch_bounds__(256, 8) void manifold_render_kernel(
    const float* __restrict__ rays_o, const float* __restrict__ rays_d,
    const float* __restrict__ levels, const float* __restrict__ W1,
    const float* __restrict__ b1, const float* __restrict__ W2,
    const float* __restrict__ b2, float* __restrict__ out, int N)
{
    // [wave][ray-half][h] : {A2, B2, rz, G};  G = 2^(B2*4*delta_ray)
    __shared__ float4 abq[4][2][Hh];

    const int tid = threadIdx.x;
    const int wave = tid >> 6;
    const int lane = tid & 63;
    const int half = lane >> 5;          // which ray of the wave's pair
    const int sl5  = lane & 31;
    const int rbase = blockIdx.x * 8 + wave * 2;
    if (rbase >= N) return;              // wave-private LDS rows: no barriers
    const int r  = rbase + half;
    const int rr = (r < N) ? r : (N - 1);   // clamp loads; stores guarded

    const float b2v = b2[0];
    float lvl[Lc];
#pragma unroll
    for (int j = 0; j < Lc; ++j) lvl[j] = levels[j];

    const float ox = rays_o[3 * rr], oy = rays_o[3 * rr + 1], oz = rays_o[3 * rr + 2];
    const float dx = rays_d[3 * rr], dy = rays_d[3 * rr + 1], dz = rays_d[3 * rr + 2];

    // sphere bounds (my ray)
    const float bq = ox * dx + oy * dy + oz * dz;
    const float cq = ox * ox + oy * oy + oz * oz - R_SPHEREf * R_SPHEREf;
    const float disc = bq * bq - cq;
    const bool hit = disc > 0.0f;
    const float sqv = __builtin_amdgcn_sqrtf(hit ? disc : 1.0f);
    const float d_near = fmaxf(-bq - sqv, NEARf);
    const float d_far  = fminf(-bq + sqv, FARf);
    const bool mask_bound = hit && (d_near < d_far);
    const float delta = (d_far - d_near) * (1.0f / 63.0f);

    // ---- setup (lane = h): write BOTH rays' per-h quads ----
    const float w1x = W1[lane], w1y = W1[Hh + lane], w1z = W1[2 * Hh + lane];
    const float w2lane = W2[lane];
    const float zq = -2.0f * w2lane;
    const float zs = copysignf(fmaxf(fabsf(zq), 1e-30f), zq);
    const float rz = __builtin_amdgcn_rcpf(zs);
    {
        // my ray's linearization for h = lane
        const float Ah = __builtin_fmaf(oz, w1z, __builtin_fmaf(oy, w1y,
                         __builtin_fmaf(ox, w1x, b1[lane])));
        const float Bh = __builtin_fmaf(dz, w1z, __builtin_fmaf(dy, w1y, dx * w1x));
        const float A2 = __builtin_fmaf(Ah, C_LO, Ah * C_HI);
        const float B2 = __builtin_fmaf(Bh, C_LO, Bh * C_HI);
        const float Gh = __builtin_amdgcn_exp2f(B2 * (4.0f * delta));
        abq[wave][half][lane] = make_float4(A2, B2, rz, Gh);
        // other ray's params via cross-half shuffle
        const float oxo = __shfl_xor(ox, 32), oyo = __shfl_xor(oy, 32), ozo = __shfl_xor(oz, 32);
        const float dxo = __shfl_xor(dx, 32), dyo = __shfl_xor(dy, 32), dzo = __shfl_xor(dz, 32);
        const float dlo = __shfl_xor(delta, 32);
        const float Aho = __builtin_fmaf(ozo, w1z, __builtin_fmaf(oyo, w1y,
                          __builtin_fmaf(oxo, w1x, b1[lane])));
        const float Bho = __builtin_fmaf(dzo, w1z, __builtin_fmaf(dyo, w1y, dxo * w1x));
        const float A2o = __builtin_fmaf(Aho, C_LO, Aho * C_HI);
        const float B2o = __builtin_fmaf(Bho, C_LO, Bho * C_HI);
        const float Gho = __builtin_amdgcn_exp2f(B2o * (4.0f * dlo));
        abq[wave][half ^ 1][lane] = make_float4(A2o, B2o, rz, Gho);
    }

    // W2SUM butterfly (ray-independent)
    float w2sum = w2lane;
#pragma unroll
    for (int m = 1; m < 64; m <<= 1) w2sum += __shfl_xor(w2sum, m);
    const float sbase = w2sum + b2v + R0f;

    // ---- main loop: per half, lane = (hg3 = (lane>>2)&7, sl2 = lane&3) ----
    // 8 h per lane (h = hg3 + 8j), 16 sample-phases (4 samples each);
    // recurrence v' = v*G + K advances 4 samples. Reduce over hg3 via
    // shfl_xor(4,8,16) (stays in-half). Keep p==hg3 -> slot A (sample
    // 4*hg3+sl2 = lane&31), p==hg3+8 -> slot B (+32). 24 state VGPRs.
    const int hg3 = (lane >> 2) & 7;
    const int sl2 = lane & 3;
    const float dsl = __builtin_fmaf((float)sl2, delta, d_near);

    const float4* __restrict__ ab = &abq[wave][half][0];
    float v[8], G[8], K[8];
#pragma unroll
    for (int j = 0; j < 8; ++j) {
        const float4 q = ab[hg3 + 8 * j];
        const float y = __builtin_fmaf(dsl, q.y, q.x);
        const float e0 = __builtin_amdgcn_exp2f(y);
        v[j] = __builtin_fmaf(e0, q.z, q.z);         // rz*(1+e0)
        G[j] = q.w;
        K[j] = __builtin_fmaf(-q.z, q.w, q.z);       // rz*(1-G)
    }

    float accA = 0.0f, accB = 0.0f;
#pragma unroll
    for (int p = 0; p < 16; ++p) {
        if (p > 0) {
#pragma unroll
            for (int j = 0; j < 8; ++j) v[j] = __builtin_fmaf(v[j], G[j], K[j]);
        }
        // two quad-rationals: 1/a+1/b+1/c+1/d = (n01*d23+n23*d01)/(d01*d23)
        float part;
        {
            const float n01 = v[0] + v[1], d01 = v[0] * v[1];
            const float n23 = v[2] + v[3], d23 = v[2] * v[3];
            const float numA = __builtin_fmaf(n23, d01, n01 * d23);
            const float denA = d01 * d23;
            const float n45 = v[4] + v[5], d45 = v[4] * v[5];
            const float n67 = v[6] + v[7], d67 = v[6] * v[7];
            const float numB = __builtin_fmaf(n67, d45, n45 * d67);
            const float denB = d45 * d67;
            part = numA * __builtin_amdgcn_rcpf(denA);
            part = __builtin_fmaf(numB, __builtin_amdgcn_rcpf(denB), part);
        }
        part += __shfl_xor(part, 4);
        part += __shfl_xor(part, 8);
        part += __shfl_xor(part, 16);
        if (p < 8)  { if (p == hg3)     accA = part; }
        else        { if (p == hg3 + 8) accB = part; }
    }

    // ---- two samples per lane: sA = sl5, sB = sl5 + 32 ----
    const float tA = (float)sl5 * (1.0f / 63.0f);
    const float dsvA = d_near * (1.0f - tA) + d_far * tA;
    const float tB = (float)(sl5 + 32) * (1.0f / 63.0f);
    const float dsvB = d_near * (1.0f - tB) + d_far * tB;
    const float xA0 = ox + dx * dsvA, xA1 = oy + dy * dsvA, xA2 = oz + dz * dsvA;
    const float xB0 = ox + dx * dsvB, xB1 = oy + dy * dsvB, xB2 = oz + dz * dsvB;
    const float nrmA = __builtin_amdgcn_sqrtf(xA0 * xA0 + xA1 * xA1 + xA2 * xA2);
    const float nrmB = __builtin_amdgcn_sqrtf(xB0 * xB0 + xB1 * xB1 + xB2 * xB2);
    const float scalA = (accA + sbase) - nrmA;
    const float scalB = (accB + sbase) - nrmB;
    const bool validA = nrmA < R_SPHEREf;
    const bool validB = nrmB < R_SPHEREf;

    // assemble per-ray 64-bit sample masks from two slot-ballots
    const u64 LO32 = 0xFFFFFFFFull;
    const u64 mInt = 0x7FFFFFFFFFFFFFFFull;      // j < 63
#define ASSEMBLE(bA, bB) (half ? (((bA) >> 32) | ((bB) & ~LO32)) \
                               : (((bA) & LO32) | ((bB) << 32)))
    const u64 bVA = __ballot(validA), bVB = __ballot(validB);
    const u64 mV  = ASSEMBLE(bVA, bVB);
    const u64 mIB = mV & (mV >> 1) & mInt;       // valid & validn & is_int

    // argmin of sc_b over intervals (first occurrence)
    float scbA = __shfl_down(scalA, 1);
    const float sB0 = __shfl(scalB, half << 5);  // my ray's sample 32
    if (sl5 == 31) scbA = sB0;
    const float scbB = __shfl_down(scalB, 1);
    const float keyA = scbA;                               // j = sl5 (<=31 < 63)
    const float keyB = (sl5 < 31) ? scbB : INFINITY;       // j = sl5+32, excl 63
    float mnv = fminf(keyA, keyB);
#pragma unroll
    for (int m = 1; m < 32; m <<= 1) mnv = fminf(mnv, __shfl_xor(mnv, m));
    const u64 eqA = __ballot(keyA == mnv), eqB = __ballot(keyB == mnv);
    const int ind_lowest = __builtin_ctzll(ASSEMBLE(eqA, eqB));

    // ---- per-level interval pick + secant init ----
    bool mintb[Lc], msec[Lc];
    float dinit[Lc];
    float g_dfs = 0.f, g_dbs = 0.f, g_sfs = 0.f, g_sbs = 0.f, g_dcur = 0.f, g_lr = 0.f;
    const int gl = (lane >> 3) & 3;              // secant: my level group

#pragma unroll
    for (int lv = 0; lv < Lc; ++lv) {
        const float l = lvl[lv];
        const u64 bLA = __ballot(scalA < l),  bLB = __ballot(scalB < l);
        const u64 bEA = __ballot(scalA == l), bEB = __ballot(scalB == l);
        const u64 bL = ASSEMBLE(bLA, bLB);
        const u64 bE = ASSEMBLE(bEA, bEB);
        const u64 bP = (bL >> 1) & mInt;         // scb_j < l
        const u64 bZ = (bE >> 1) & mInt;         // scb_j == l
        const u64 bI = (~bL) & (bP | bZ) & mIB;  // in-interval
        const int ind_closest = bP ? __builtin_ctzll(bP)
                                   : (bZ ? __builtin_ctzll(bZ) : (Sn - 2));
        const int idx  = bI ? ind_closest : ind_lowest;
        const int idx1 = idx + 1;

        // gather scal[idx], scal[idx+1] of my ray (2 shfl + select each)
        const int src0 = (half << 5) | (idx & 31);
        const float sfA = __shfl(scalA, src0), sfB = __shfl(scalB, src0);
        const float s_front = (idx < 32) ? sfA : sfB;
        const int src1 = (half << 5) | (idx1 & 31);
        const float sbA2 = __shfl(scalA, src1), sbB2 = __shfl(scalB, src1);
        const float s_back = (idx1 < 32) ? sbA2 : sbB2;

        // dsv is affine in idx: compute, don't gather
        const float tf = (float)idx  * (1.0f / 63.0f);
        const float d_front = d_near * (1.0f - tf) + d_far * tf;
        const float tb = (float)idx1 * (1.0f / 63.0f);
        const float d_back  = d_near * (1.0f - tb) + d_far * tb;

        const bool mi = (s_front >= l) && (l >= s_back);
        const float sd = s_front - s_back;
        const bool vd = fabsf(sd) > EPSf;
        const bool ms = mi && vd;
        const float d_sec = fastdiv((l - s_back) * d_front + (s_front - l) * d_back,
                                    vd ? sd : 1.0f);
        const float di = ms ? d_sec : d_back;

        mintb[lv] = mi; msec[lv] = ms; dinit[lv] = di;
        if (gl == lv) {
            g_dfs = d_front; g_dbs = d_back; g_sfs = s_front; g_sbs = s_back;
            g_dcur = di; g_lr = l;
        }
    }

    // ---- secant: 8 groups of 8 lanes = 2 rays x 4 levels, 8 h per lane ----
    // VGPR diet: fragments are RE-READ from LDS each iteration (broadcast,
    // conflict-free) instead of caching 24-32 regs — this is what lets the
    // (256,8) bound fit without spilling (r8 lesson). Rolled loop + memory
    // clobber defeat LICM re-hoisting of the loads.
    const int sub = lane & 7;
    const float4* __restrict__ ab2 = &abq[wave][half][0];

#pragma unroll 1
    for (int it = 0; it < SECANT_STEPS; ++it) {
        asm volatile("" ::: "memory");   // keep fragment reads inside the loop
        const float mx0 = ox + g_dcur * dx, mx1 = oy + g_dcur * dy, mx2 = oz + g_dcur * dz;
        const float mn = __builtin_amdgcn_sqrtf(mx0 * mx0 + mx1 * mx1 + mx2 * mx2);
        float vv[8];
#pragma unroll
        for (int j = 0; j < 8; ++j) {
            const float4 q = ab2[sub + 8 * j];
            const float y = __builtin_fmaf(g_dcur, q.y, q.x);
            const float e = __builtin_amdgcn_exp2f(y);
            vv[j] = __builtin_fmaf(e, q.z, q.z);
        }
        // 4 independent pair-rationals, balanced combine
        float tp[4];
#pragma unroll
        for (int p = 0; p < 4; ++p) {
            const float n = vv[2 * p] + vv[2 * p + 1];
            const float d = vv[2 * p] * vv[2 * p + 1];
            tp[p] = n * __builtin_amdgcn_rcpf(d);
        }
        float part = (tp[0] + tp[1]) + (tp[2] + tp[3]);
        part += __shfl_xor(part, 1);
        part += __shfl_xor(part, 2);
        part += __shfl_xor(part, 4);
        const float s_mid = (part + sbase) - mn;
        const bool mv = mn < R_SPHEREf;
        const bool upf = (s_mid > g_lr) && mv;
        const bool upb = (s_mid < g_lr) && mv;
        if (upf) { g_dfs = g_dcur; g_sfs = s_mid; }
        if (upb) { g_dbs = g_dcur; g_sbs = s_mid; }
        const float sd2 = g_sfs - g_sbs;
        const bool ok = fabsf(sd2) > EPSf;
        if (ok) g_dcur = fastdiv((g_lr - g_sbs) * g_dfs + (g_sfs - g_lr) * g_dbs, sd2);
    }

    // gather my ray's per-level results (groups at half*32 + 8*lv)
    float v0g, v1g, v2g, v3g;
    {
        const int gb = half << 5;
        const float dc0 = __shfl(g_dcur, gb);
        const float dc1 = __shfl(g_dcur, gb + 8);
        const float dc2 = __shfl(g_dcur, gb + 16);
        const float dc3 = __shfl(g_dcur, gb + 24);
        v0g = msec[0] ? dc0 : dinit[0];
        v1g = msec[1] ? dc1 : dinit[1];
        v2g = msec[2] ? dc2 : dinit[2];
        v3g = msec[3] ? dc3 : dinit[3];
    }
    int m0 = mintb[0], m1 = mintb[1], m2 = mintb[2], m3 = mintb[3];
    int i0 = 0, i1 = 1, i2 = 2, i3 = 3;

    // stable sort of 4 by (value, original index) — 5-comparator network
#define CSWAP(va, ia, ma, vb, ib, mb)                                    \
    { bool sw = (vb < va) || (vb == va && ib < ia);                      \
      if (sw) { float tv = va; va = vb; vb = tv;                         \
                int ti = ia; ia = ib; ib = ti;                           \
                int tm = ma; ma = mb; mb = tm; } }
    CSWAP(v0g, i0, m0, v1g, i1, m1);
    CSWAP(v2g, i2, m2, v3g, i3, m3);
    CSWAP(v0g, i0, m0, v2g, i2, m2);
    CSWAP(v1g, i1, m1, v3g, i3, m3);
    CSWAP(v1g, i1, m1, v2g, i2, m2);
#undef CSWAP

    const long long NL = (long long)N * Lc;
    if (sl5 < 2 * Lc && r < N) {
        const int k = sl5 & 3;
        const float dvs = (k == 0) ? v0g : (k == 1) ? v1g : (k == 2) ? v2g : v3g;
        const int   mms = (k == 0) ? m0 : (k == 1) ? m1 : (k == 2) ? m2 : m3;
        const bool isd = sl5 < Lc;
        const float val = isd ? (mask_bound ? dvs : 0.0f)
                              : ((mms && mask_bound) ? 1.0f : 0.0f);
        const long long off = (long long)r * Lc + k + (isd ? 0LL : NL);
        out[off] = val;
    }
}

extern "C" void kernel_launch(void* const* d_in, const int* in_sizes, int n_in,
                              void* d_out, int out_size, void* d_ws, size_t ws_size,
                              hipStream_t stream) {
    const float* rays_o = (const float*)d_in[0];
    const float* rays_d = (const float*)d_in[1];
    const float* levels = (const float*)d_in[2];
    const float* W1 = (const float*)d_in[3];
    const float* b1 = (const float*)d_in[4];
    const float* W2 = (const float*)d_in[5];
    const float* b2 = (const float*)d_in[6];
    float* out = (float*)d_out;

    const int N = in_sizes[0] / 3;          // B*R rays
    const int blocks = (N + 7) / 8;         // 4 waves x 2 rays per 256-thread block
    manifold_render_kernel<<<blocks, 256, 0, stream>>>(
        rays_o, rays_d, levels, W1, b1, W2, b2, out, N);
}

// Round 11
// 106.723 us; speedup vs baseline: 1.9483x; 1.9483x over previous
//
#include <hip/hip_runtime.h>
#include <cstdint>

#define R_SPHEREf 3.0f
#define NEARf 0.0f
#define FARf 100.0f
#define SECANT_STEPS 4
#define EPSf 1e-4f
#define R0f 1.0f
#define Hh 64
#define Lc 4
#define Sn 64

// tanh via: w2*tanh(x) = w2 + z/(1+exp2(C*x)),  z = -2*w2, C = 2*log2(e).
#define C_HI 2.88539004325866699f   // float-nearest 2*log2(e)
#define C_LO 3.8519227871e-08f      // residual for fma correction

typedef unsigned long long u64;

// x/y via v_rcp_f32 + 1 Newton step
__device__ __forceinline__ float fastdiv(float a, float b) {
    float rcp = __builtin_amdgcn_rcpf(b);
    rcp = __builtin_fmaf(rcp, __builtin_fmaf(-b, rcp, 1.0f), rcp);
    return a * rcp;
}

// r7 restoration (43.7 us, best proven). VGPR lands at 80 -> 4 waves/SIMD.
// Do NOT add a min-waves launch bound: the epilogue live-set is >64 VGPR
// (divergent u64 masks, per-level state, recurrence overlap) and forcing
// 8 waves/SIMD spills catastrophically (r8: 230/444 MB scratch; r10: same
// with secant LDS-diet). The 65-128 tier is this structure's floor.
__global__ __launch_bounds__(256) void manifold_render_kernel(
    const float* __restrict__ rays_o, const float* __restrict__ rays_d,
    const float* __restrict__ levels, const float* __restrict__ W1,
    const float* __restrict__ b1, const float* __restrict__ W2,
    const float* __restrict__ b2, float* __restrict__ out, int N)
{
    // [wave][ray-half][h] : {A2, B2, rz, G};  G = 2^(B2*8*delta_ray)
    __shared__ float4 abq[4][2][Hh];

    const int tid = threadIdx.x;
    const int wave = tid >> 6;
    const int lane = tid & 63;
    const int half = lane >> 5;          // which ray of the wave's pair
    const int sl5  = lane & 31;
    const int rbase = blockIdx.x * 8 + wave * 2;
    if (rbase >= N) return;              // wave-private LDS rows: no barriers
    const int r  = rbase + half;
    const int rr = (r < N) ? r : (N - 1);   // clamp loads; stores guarded

    const float b2v = b2[0];
    float lvl[Lc];
#pragma unroll
    for (int j = 0; j < Lc; ++j) lvl[j] = levels[j];

    const float ox = rays_o[3 * rr], oy = rays_o[3 * rr + 1], oz = rays_o[3 * rr + 2];
    const float dx = rays_d[3 * rr], dy = rays_d[3 * rr + 1], dz = rays_d[3 * rr + 2];

    // sphere bounds (my ray)
    const float bq = ox * dx + oy * dy + oz * dz;
    const float cq = ox * ox + oy * oy + oz * oz - R_SPHEREf * R_SPHEREf;
    const float disc = bq * bq - cq;
    const bool hit = disc > 0.0f;
    const float sqv = __builtin_amdgcn_sqrtf(hit ? disc : 1.0f);
    const float d_near = fmaxf(-bq - sqv, NEARf);
    const float d_far  = fminf(-bq + sqv, FARf);
    const bool mask_bound = hit && (d_near < d_far);
    const float delta = (d_far - d_near) * (1.0f / 63.0f);

    // ---- setup (lane = h): write BOTH rays' per-h quads ----
    const float w1x = W1[lane], w1y = W1[Hh + lane], w1z = W1[2 * Hh + lane];
    const float w2lane = W2[lane];
    const float zq = -2.0f * w2lane;
    const float zs = copysignf(fmaxf(fabsf(zq), 1e-30f), zq);
    const float rz = __builtin_amdgcn_rcpf(zs);
    {
        // my ray's linearization for h = lane
        const float Ah = __builtin_fmaf(oz, w1z, __builtin_fmaf(oy, w1y,
                         __builtin_fmaf(ox, w1x, b1[lane])));
        const float Bh = __builtin_fmaf(dz, w1z, __builtin_fmaf(dy, w1y, dx * w1x));
        const float A2 = __builtin_fmaf(Ah, C_LO, Ah * C_HI);
        const float B2 = __builtin_fmaf(Bh, C_LO, Bh * C_HI);
        const float Gh = __builtin_amdgcn_exp2f(B2 * (8.0f * delta));
        abq[wave][half][lane] = make_float4(A2, B2, rz, Gh);
        // other ray's params via cross-half shuffle
        const float oxo = __shfl_xor(ox, 32), oyo = __shfl_xor(oy, 32), ozo = __shfl_xor(oz, 32);
        const float dxo = __shfl_xor(dx, 32), dyo = __shfl_xor(dy, 32), dzo = __shfl_xor(dz, 32);
        const float dlo = __shfl_xor(delta, 32);
        const float Aho = __builtin_fmaf(ozo, w1z, __builtin_fmaf(oyo, w1y,
                          __builtin_fmaf(oxo, w1x, b1[lane])));
        const float Bho = __builtin_fmaf(dzo, w1z, __builtin_fmaf(dyo, w1y, dxo * w1x));
        const float A2o = __builtin_fmaf(Aho, C_LO, Aho * C_HI);
        const float B2o = __builtin_fmaf(Bho, C_LO, Bho * C_HI);
        const float Gho = __builtin_amdgcn_exp2f(B2o * (8.0f * dlo));
        abq[wave][half ^ 1][lane] = make_float4(A2o, B2o, rz, Gho);
    }

    // W2SUM butterfly (ray-independent)
    float w2sum = w2lane;
#pragma unroll
    for (int m = 1; m < 64; m <<= 1) w2sum += __shfl_xor(w2sum, m);
    const float sbase = w2sum + b2v + R0f;

    // ---- main loop: per half, lane = (hg2 = (lane>>3)&3, sl = lane&7) ----
    // 16 h per lane (h = hg2 + 4j), 8 sample-phases; recurrence v' = v*G + K.
    // Reduce over hg2 (xor 8,16 — stays in-half); keep it==hg2 -> slot A
    // (sample lane&31), it==hg2+4 -> slot B (sample (lane&31)+32).
    const int hg2 = (lane >> 3) & 3;
    const int sl  = lane & 7;
    const float dsl = __builtin_fmaf((float)sl, delta, d_near);

    const float4* __restrict__ ab = &abq[wave][half][0];
    float v[16], G[16], K[16];
#pragma unroll
    for (int j = 0; j < 16; ++j) {
        const float4 q = ab[hg2 + 4 * j];
        const float y = __builtin_fmaf(dsl, q.y, q.x);
        const float e0 = __builtin_amdgcn_exp2f(y);
        v[j] = __builtin_fmaf(e0, q.z, q.z);         // rz*(1+e0)
        G[j] = q.w;
        K[j] = __builtin_fmaf(-q.z, q.w, q.z);       // rz*(1-G)
    }

    float accA = 0.0f, accB = 0.0f;
#pragma unroll
    for (int it = 0; it < 8; ++it) {
        if (it > 0) {
#pragma unroll
            for (int j = 0; j < 16; ++j) v[j] = __builtin_fmaf(v[j], G[j], K[j]);
        }
        float part;
        {   // 4 quad-rationals over j-quads, balanced combine
            float tq[4];
#pragma unroll
            for (int qd = 0; qd < 4; ++qd) {
                const float a = v[4 * qd], b = v[4 * qd + 1];
                const float c = v[4 * qd + 2], d = v[4 * qd + 3];
                const float n01 = a + b, d01 = a * b;
                const float n23 = c + d, d23 = c * d;
                const float num = __builtin_fmaf(n23, d01, n01 * d23);
                const float den = d01 * d23;
                tq[qd] = num * __builtin_amdgcn_rcpf(den);
            }
            part = (tq[0] + tq[1]) + (tq[2] + tq[3]);
        }
        part += __shfl_xor(part, 8);
        part += __shfl_xor(part, 16);
        if (it == hg2)     accA = part;
        if (it == hg2 + 4) accB = part;
    }

    // ---- two samples per lane: sA = sl5, sB = sl5 + 32 ----
    const float tA = (float)sl5 * (1.0f / 63.0f);
    const float dsvA = d_near * (1.0f - tA) + d_far * tA;
    const float tB = (float)(sl5 + 32) * (1.0f / 63.0f);
    const float dsvB = d_near * (1.0f - tB) + d_far * tB;
    const float xA0 = ox + dx * dsvA, xA1 = oy + dy * dsvA, xA2 = oz + dz * dsvA;
    const float xB0 = ox + dx * dsvB, xB1 = oy + dy * dsvB, xB2 = oz + dz * dsvB;
    const float nrmA = __builtin_amdgcn_sqrtf(xA0 * xA0 + xA1 * xA1 + xA2 * xA2);
    const float nrmB = __builtin_amdgcn_sqrtf(xB0 * xB0 + xB1 * xB1 + xB2 * xB2);
    const float scalA = (accA + sbase) - nrmA;
    const float scalB = (accB + sbase) - nrmB;
    const bool validA = nrmA < R_SPHEREf;
    const bool validB = nrmB < R_SPHEREf;

    // assemble per-ray 64-bit sample masks from two slot-ballots
    const u64 LO32 = 0xFFFFFFFFull;
    const u64 mInt = 0x7FFFFFFFFFFFFFFFull;      // j < 63
#define ASSEMBLE(bA, bB) (half ? (((bA) >> 32) | ((bB) & ~LO32)) \
                               : (((bA) & LO32) | ((bB) << 32)))
    const u64 bVA = __ballot(validA), bVB = __ballot(validB);
    const u64 mV  = ASSEMBLE(bVA, bVB);
    const u64 mIB = mV & (mV >> 1) & mInt;       // valid & validn & is_int

    // argmin of sc_b over intervals (first occurrence)
    float scbA = __shfl_down(scalA, 1);
    const float sB0 = __shfl(scalB, half << 5);  // my ray's sample 32
    if (sl5 == 31) scbA = sB0;
    const float scbB = __shfl_down(scalB, 1);
    const float keyA = scbA;                               // j = sl5 (<=31 < 63)
    const float keyB = (sl5 < 31) ? scbB : INFINITY;       // j = sl5+32, excl 63
    float mnv = fminf(keyA, keyB);
#pragma unroll
    for (int m = 1; m < 32; m <<= 1) mnv = fminf(mnv, __shfl_xor(mnv, m));
    const u64 eqA = __ballot(keyA == mnv), eqB = __ballot(keyB == mnv);
    const int ind_lowest = __builtin_ctzll(ASSEMBLE(eqA, eqB));

    // ---- per-level interval pick + secant init ----
    bool mintb[Lc], msec[Lc];
    float dinit[Lc];
    float g_dfs = 0.f, g_dbs = 0.f, g_sfs = 0.f, g_sbs = 0.f, g_dcur = 0.f, g_lr = 0.f;
    const int gl = (lane >> 3) & 3;              // secant: my level group

#pragma unroll
    for (int lv = 0; lv < Lc; ++lv) {
        const float l = lvl[lv];
        const u64 bLA = __ballot(scalA < l),  bLB = __ballot(scalB < l);
        const u64 bEA = __ballot(scalA == l), bEB = __ballot(scalB == l);
        const u64 bL = ASSEMBLE(bLA, bLB);
        const u64 bE = ASSEMBLE(bEA, bEB);
        const u64 bP = (bL >> 1) & mInt;         // scb_j < l
        const u64 bZ = (bE >> 1) & mInt;         // scb_j == l
        const u64 bI = (~bL) & (bP | bZ) & mIB;  // in-interval
        const int ind_closest = bP ? __builtin_ctzll(bP)
                                   : (bZ ? __builtin_ctzll(bZ) : (Sn - 2));
        const int idx  = bI ? ind_closest : ind_lowest;
        const int idx1 = idx + 1;

        // gather scal[idx], scal[idx+1] of my ray (2 shfl + select each)
        const int src0 = (half << 5) | (idx & 31);
        const float sfA = __shfl(scalA, src0), sfB = __shfl(scalB, src0);
        const float s_front = (idx < 32) ? sfA : sfB;
        const int src1 = (half << 5) | (idx1 & 31);
        const float sbA2 = __shfl(scalA, src1), sbB2 = __shfl(scalB, src1);
        const float s_back = (idx1 < 32) ? sbA2 : sbB2;

        // dsv is affine in idx: compute, don't gather
        const float tf = (float)idx  * (1.0f / 63.0f);
        const float d_front = d_near * (1.0f - tf) + d_far * tf;
        const float tb = (float)idx1 * (1.0f / 63.0f);
        const float d_back  = d_near * (1.0f - tb) + d_far * tb;

        const bool mi = (s_front >= l) && (l >= s_back);
        const float sd = s_front - s_back;
        const bool vd = fabsf(sd) > EPSf;
        const bool ms = mi && vd;
        const float d_sec = fastdiv((l - s_back) * d_front + (s_front - l) * d_back,
                                    vd ? sd : 1.0f);
        const float di = ms ? d_sec : d_back;

        mintb[lv] = mi; msec[lv] = ms; dinit[lv] = di;
        if (gl == lv) {
            g_dfs = d_front; g_dbs = d_back; g_sfs = s_front; g_sbs = s_back;
            g_dcur = di; g_lr = l;
        }
    }

    // ---- secant: 8 groups of 8 lanes = 2 rays x 4 levels, 8 h per lane ----
    const int sub = lane & 7;
    const float4* __restrict__ ab2 = &abq[wave][half][0];
    float4 sq[8];
#pragma unroll
    for (int j = 0; j < 8; ++j) sq[j] = ab2[sub + 8 * j];

#pragma unroll
    for (int it = 0; it < SECANT_STEPS; ++it) {
        const float mx0 = ox + g_dcur * dx, mx1 = oy + g_dcur * dy, mx2 = oz + g_dcur * dz;
        const float mn = __builtin_amdgcn_sqrtf(mx0 * mx0 + mx1 * mx1 + mx2 * mx2);
        float vv[8];
#pragma unroll
        for (int j = 0; j < 8; ++j) {
            const float y = __builtin_fmaf(g_dcur, sq[j].y, sq[j].x);
            const float e = __builtin_amdgcn_exp2f(y);
            vv[j] = __builtin_fmaf(e, sq[j].z, sq[j].z);
        }
        // 4 independent pair-rationals, balanced combine
        float tp[4];
#pragma unroll
        for (int p = 0; p < 4; ++p) {
            const float n = vv[2 * p] + vv[2 * p + 1];
            const float d = vv[2 * p] * vv[2 * p + 1];
            tp[p] = n * __builtin_amdgcn_rcpf(d);
        }
        float part = (tp[0] + tp[1]) + (tp[2] + tp[3]);
        part += __shfl_xor(part, 1);
        part += __shfl_xor(part, 2);
        part += __shfl_xor(part, 4);
        const float s_mid = (part + sbase) - mn;
        const bool mv = mn < R_SPHEREf;
        const bool upf = (s_mid > g_lr) && mv;
        const bool upb = (s_mid < g_lr) && mv;
        if (upf) { g_dfs = g_dcur; g_sfs = s_mid; }
        if (upb) { g_dbs = g_dcur; g_sbs = s_mid; }
        const float sd2 = g_sfs - g_sbs;
        const bool ok = fabsf(sd2) > EPSf;
        if (ok) g_dcur = fastdiv((g_lr - g_sbs) * g_dfs + (g_sfs - g_lr) * g_dbs, sd2);
    }

    // gather my ray's per-level results (groups at half*32 + 8*lv)
    float v0g, v1g, v2g, v3g;
    {
        const int gb = half << 5;
        const float dc0 = __shfl(g_dcur, gb);
        const float dc1 = __shfl(g_dcur, gb + 8);
        const float dc2 = __shfl(g_dcur, gb + 16);
        const float dc3 = __shfl(g_dcur, gb + 24);
        v0g = msec[0] ? dc0 : dinit[0];
        v1g = msec[1] ? dc1 : dinit[1];
        v2g = msec[2] ? dc2 : dinit[2];
        v3g = msec[3] ? dc3 : dinit[3];
    }
    int m0 = mintb[0], m1 = mintb[1], m2 = mintb[2], m3 = mintb[3];
    int i0 = 0, i1 = 1, i2 = 2, i3 = 3;

    // stable sort of 4 by (value, original index) — 5-comparator network
#define CSWAP(va, ia, ma, vb, ib, mb)                                    \
    { bool sw = (vb < va) || (vb == va && ib < ia);                      \
      if (sw) { float tv = va; va = vb; vb = tv;                         \
                int ti = ia; ia = ib; ib = ti;                           \
                int tm = ma; ma = mb; mb = tm; } }
    CSWAP(v0g, i0, m0, v1g, i1, m1);
    CSWAP(v2g, i2, m2, v3g, i3, m3);
    CSWAP(v0g, i0, m0, v2g, i2, m2);
    CSWAP(v1g, i1, m1, v3g, i3, m3);
    CSWAP(v1g, i1, m1, v2g, i2, m2);
#undef CSWAP

    const long long NL = (long long)N * Lc;
    if (sl5 < 2 * Lc && r < N) {
        const int k = sl5 & 3;
        const float dvs = (k == 0) ? v0g : (k == 1) ? v1g : (k == 2) ? v2g : v3g;
        const int   mms = (k == 0) ? m0 : (k == 1) ? m1 : (k == 2) ? m2 : m3;
        const bool isd = sl5 < Lc;
        const float val = isd ? (mask_bound ? dvs : 0.0f)
                              : ((mms && mask_bound) ? 1.0f : 0.0f);
        const long long off = (long long)r * Lc + k + (isd ? 0LL : NL);
        out[off] = val;
    }
}

extern "C" void kernel_launch(void* const* d_in, const int* in_sizes, int n_in,
                              void* d_out, int out_size, void* d_ws, size_t ws_size,
                              hipStream_t stream) {
    const float* rays_o = (const float*)d_in[0];
    const float* rays_d = (const float*)d_in[1];
    const float* levels = (const float*)d_in[2];
    const float* W1 = (const float*)d_in[3];
    const float* b1 = (const float*)d_in[4];
    const float* W2 = (const float*)d_in[5];
    const float* b2 = (const float*)d_in[6];
    float* out = (float*)d_out;

    const int N = in_sizes[0] / 3;          // B*R rays
    const int blocks = (N + 7) / 8;         // 4 waves x 2 rays per 256-thread block
    manifold_render_kernel<<<blocks, 256, 0, stream>>>(
        rays_o, rays_d, levels, W1, b1, W2, b2, out, N);
}

// Round 12
// 104.260 us; speedup vs baseline: 1.9943x; 1.0236x over previous
//
#include <hip/hip_runtime.h>
#include <cstdint>

#define R_SPHEREf 3.0f
#define NEARf 0.0f
#define FARf 100.0f
#define SECANT_STEPS 4
#define EPSf 1e-4f
#define R0f 1.0f
#define Hh 64
#define Lc 4
#define Sn 64

// tanh via: w2*tanh(x) = w2 + z/(1+exp2(C*x)),  z = -2*w2, C = 2*log2(e).
#define C_HI 2.88539004325866699f   // float-nearest 2*log2(e)
#define C_LO 3.8519227871e-08f      // residual for fma correction

typedef unsigned long long u64;

// x/y via v_rcp_f32 + 1 Newton step
__device__ __forceinline__ float fastdiv(float a, float b) {
    float rcp = __builtin_amdgcn_rcpf(b);
    rcp = __builtin_fmaf(rcp, __builtin_fmaf(-b, rcp, 1.0f), rcp);
    return a * rcp;
}

// ---- VALU lane-permutes for butterfly reduces (replace ds_swizzle) ----
// __shfl_xor -> ds_swizzle/bpermute = DS pipe, ~40cy + lgkmcnt wait on a
// SERIAL reduce chain; with 4 phase-synced waves/SIMD this is the 28%
// VALU-idle (r11 counters). DPP/permlane are ~2cy VALU ops.
template <int CTRL>
__device__ __forceinline__ float dpp_mov(float x) {
    return __int_as_float(
        __builtin_amdgcn_update_dpp(0, __float_as_int(x), CTRL, 0xF, 0xF, true));
}
#define DPP_XOR1(x) dpp_mov<0xB1>(x)    // quad_perm [1,0,3,2]
#define DPP_XOR2(x) dpp_mov<0x4E>(x)    // quad_perm [2,3,0,1]
#define DPP_XOR8(x) dpp_mov<0x128>(x)   // row_ror:8 ((i+8)%16 == i^8)

// xor16 via v_permlane16_swap_b32: with both inputs = x the output pair at
// each lane is {x, x[lane^16]} (order depends on swap direction convention)
// -> symmetric combines (sum/min) are convention-free.
#if defined(__has_builtin) && __has_builtin(__builtin_amdgcn_permlane16_swap)
__device__ __forceinline__ float plane16_sum(float x) {
    auto pr = __builtin_amdgcn_permlane16_swap(__float_as_uint(x),
                                               __float_as_uint(x), false, false);
    return __uint_as_float(pr[0]) + __uint_as_float(pr[1]);
}
__device__ __forceinline__ float plane16_min(float x) {
    auto pr = __builtin_amdgcn_permlane16_swap(__float_as_uint(x),
                                               __float_as_uint(x), false, false);
    return fminf(__uint_as_float(pr[0]), __uint_as_float(pr[1]));
}
#else
__device__ __forceinline__ float plane16_sum(float x) { return x + __shfl_xor(x, 16); }
__device__ __forceinline__ float plane16_min(float x) { return fminf(x, __shfl_xor(x, 16)); }
#endif

// r7 structure (43.7us proven). VGPR ~80 -> 4 waves/SIMD. Do NOT add a
// min-waves launch bound: epilogue live-set >64 VGPR; forcing 8 waves/SIMD
// spills catastrophically (r8/r10: 200+/430+ MB scratch traffic).
__global__ __launch_bounds__(256) void manifold_render_kernel(
    const float* __restrict__ rays_o, const float* __restrict__ rays_d,
    const float* __restrict__ levels, const float* __restrict__ W1,
    const float* __restrict__ b1, const float* __restrict__ W2,
    const float* __restrict__ b2, float* __restrict__ out, int N)
{
    // [wave][ray-half][h] : {A2, B2, rz, G};  G = 2^(B2*8*delta_ray)
    __shared__ float4 abq[4][2][Hh];

    const int tid = threadIdx.x;
    const int wave = tid >> 6;
    const int lane = tid & 63;
    const int half = lane >> 5;          // which ray of the wave's pair
    const int sl5  = lane & 31;
    const int rbase = blockIdx.x * 8 + wave * 2;
    if (rbase >= N) return;              // wave-private LDS rows: no barriers
    const int r  = rbase + half;
    const int rr = (r < N) ? r : (N - 1);   // clamp loads; stores guarded

    const float b2v = b2[0];
    float lvl[Lc];
#pragma unroll
    for (int j = 0; j < Lc; ++j) lvl[j] = levels[j];

    const float ox = rays_o[3 * rr], oy = rays_o[3 * rr + 1], oz = rays_o[3 * rr + 2];
    const float dx = rays_d[3 * rr], dy = rays_d[3 * rr + 1], dz = rays_d[3 * rr + 2];

    // sphere bounds (my ray)
    const float bq = ox * dx + oy * dy + oz * dz;
    const float cq = ox * ox + oy * oy + oz * oz - R_SPHEREf * R_SPHEREf;
    const float disc = bq * bq - cq;
    const bool hit = disc > 0.0f;
    const float sqv = __builtin_amdgcn_sqrtf(hit ? disc : 1.0f);
    const float d_near = fmaxf(-bq - sqv, NEARf);
    const float d_far  = fminf(-bq + sqv, FARf);
    const bool mask_bound = hit && (d_near < d_far);
    const float delta = (d_far - d_near) * (1.0f / 63.0f);

    // ---- setup (lane = h): write BOTH rays' per-h quads ----
    const float w1x = W1[lane], w1y = W1[Hh + lane], w1z = W1[2 * Hh + lane];
    const float w2lane = W2[lane];
    const float zq = -2.0f * w2lane;
    const float zs = copysignf(fmaxf(fabsf(zq), 1e-30f), zq);
    const float rz = __builtin_amdgcn_rcpf(zs);
    {
        // my ray's linearization for h = lane
        const float Ah = __builtin_fmaf(oz, w1z, __builtin_fmaf(oy, w1y,
                         __builtin_fmaf(ox, w1x, b1[lane])));
        const float Bh = __builtin_fmaf(dz, w1z, __builtin_fmaf(dy, w1y, dx * w1x));
        const float A2 = __builtin_fmaf(Ah, C_LO, Ah * C_HI);
        const float B2 = __builtin_fmaf(Bh, C_LO, Bh * C_HI);
        const float Gh = __builtin_amdgcn_exp2f(B2 * (8.0f * delta));
        abq[wave][half][lane] = make_float4(A2, B2, rz, Gh);
        // other ray's params via cross-half shuffle (setup-only, keep shfl)
        const float oxo = __shfl_xor(ox, 32), oyo = __shfl_xor(oy, 32), ozo = __shfl_xor(oz, 32);
        const float dxo = __shfl_xor(dx, 32), dyo = __shfl_xor(dy, 32), dzo = __shfl_xor(dz, 32);
        const float dlo = __shfl_xor(delta, 32);
        const float Aho = __builtin_fmaf(ozo, w1z, __builtin_fmaf(oyo, w1y,
                          __builtin_fmaf(oxo, w1x, b1[lane])));
        const float Bho = __builtin_fmaf(dzo, w1z, __builtin_fmaf(dyo, w1y, dxo * w1x));
        const float A2o = __builtin_fmaf(Aho, C_LO, Aho * C_HI);
        const float B2o = __builtin_fmaf(Bho, C_LO, Bho * C_HI);
        const float Gho = __builtin_amdgcn_exp2f(B2o * (8.0f * dlo));
        abq[wave][half ^ 1][lane] = make_float4(A2o, B2o, rz, Gho);
    }

    // W2SUM butterfly (ray-independent, once — keep shfl)
    float w2sum = w2lane;
#pragma unroll
    for (int m = 1; m < 64; m <<= 1) w2sum += __shfl_xor(w2sum, m);
    const float sbase = w2sum + b2v + R0f;

    // ---- main loop: per half, lane = (hg2 = (lane>>3)&3, sl = lane&7) ----
    // 16 h per lane (h = hg2 + 4j), 8 sample-phases; recurrence v' = v*G + K.
    // Reduce over hg2 via DPP row_ror:8 + permlane16_swap (pure VALU, no DS).
    const int hg2 = (lane >> 3) & 3;
    const int sl  = lane & 7;
    const float dsl = __builtin_fmaf((float)sl, delta, d_near);

    const float4* __restrict__ ab = &abq[wave][half][0];
    float v[16], G[16], K[16];
#pragma unroll
    for (int j = 0; j < 16; ++j) {
        const float4 q = ab[hg2 + 4 * j];
        const float y = __builtin_fmaf(dsl, q.y, q.x);
        const float e0 = __builtin_amdgcn_exp2f(y);
        v[j] = __builtin_fmaf(e0, q.z, q.z);         // rz*(1+e0)
        G[j] = q.w;
        K[j] = __builtin_fmaf(-q.z, q.w, q.z);       // rz*(1-G)
    }

    float accA = 0.0f, accB = 0.0f;
#pragma unroll
    for (int it = 0; it < 8; ++it) {
        if (it > 0) {
#pragma unroll
            for (int j = 0; j < 16; ++j) v[j] = __builtin_fmaf(v[j], G[j], K[j]);
        }
        float part;
        {   // 4 quad-rationals over j-quads, balanced combine
            float tq[4];
#pragma unroll
            for (int qd = 0; qd < 4; ++qd) {
                const float a = v[4 * qd], b = v[4 * qd + 1];
                const float c = v[4 * qd + 2], d = v[4 * qd + 3];
                const float n01 = a + b, d01 = a * b;
                const float n23 = c + d, d23 = c * d;
                const float num = __builtin_fmaf(n23, d01, n01 * d23);
                const float den = d01 * d23;
                tq[qd] = num * __builtin_amdgcn_rcpf(den);
            }
            part = (tq[0] + tq[1]) + (tq[2] + tq[3]);
        }
        part += DPP_XOR8(part);          // was shfl_xor(part, 8)
        part = plane16_sum(part);        // was part += shfl_xor(part, 16)
        if (it == hg2)     accA = part;
        if (it == hg2 + 4) accB = part;
    }

    // ---- two samples per lane: sA = sl5, sB = sl5 + 32 ----
    const float tA = (float)sl5 * (1.0f / 63.0f);
    const float dsvA = d_near * (1.0f - tA) + d_far * tA;
    const float tB = (float)(sl5 + 32) * (1.0f / 63.0f);
    const float dsvB = d_near * (1.0f - tB) + d_far * tB;
    const float xA0 = ox + dx * dsvA, xA1 = oy + dy * dsvA, xA2 = oz + dz * dsvA;
    const float xB0 = ox + dx * dsvB, xB1 = oy + dy * dsvB, xB2 = oz + dz * dsvB;
    const float nrmA = __builtin_amdgcn_sqrtf(xA0 * xA0 + xA1 * xA1 + xA2 * xA2);
    const float nrmB = __builtin_amdgcn_sqrtf(xB0 * xB0 + xB1 * xB1 + xB2 * xB2);
    const float scalA = (accA + sbase) - nrmA;
    const float scalB = (accB + sbase) - nrmB;
    const bool validA = nrmA < R_SPHEREf;
    const bool validB = nrmB < R_SPHEREf;

    // assemble per-ray 64-bit sample masks from two slot-ballots
    const u64 LO32 = 0xFFFFFFFFull;
    const u64 mInt = 0x7FFFFFFFFFFFFFFFull;      // j < 63
#define ASSEMBLE(bA, bB) (half ? (((bA) >> 32) | ((bB) & ~LO32)) \
                               : (((bA) & LO32) | ((bB) << 32)))
    const u64 bVA = __ballot(validA), bVB = __ballot(validB);
    const u64 mV  = ASSEMBLE(bVA, bVB);
    const u64 mIB = mV & (mV >> 1) & mInt;       // valid & validn & is_int

    // argmin of sc_b over intervals (first occurrence); min chain on VALU
    float scbA = __shfl_down(scalA, 1);          // cross-row: keep DS
    const float sB0 = __shfl(scalB, half << 5);  // my ray's sample 32
    if (sl5 == 31) scbA = sB0;
    const float scbB = __shfl_down(scalB, 1);
    const float keyA = scbA;                               // j = sl5 (<=31 < 63)
    const float keyB = (sl5 < 31) ? scbB : INFINITY;       // j = sl5+32, excl 63
    float mnv = fminf(keyA, keyB);
    mnv = fminf(mnv, DPP_XOR1(mnv));
    mnv = fminf(mnv, DPP_XOR2(mnv));
    mnv = fminf(mnv, __shfl_xor(mnv, 4));        // no DPP16 for xor4 on CDNA
    mnv = fminf(mnv, DPP_XOR8(mnv));
    mnv = plane16_min(mnv);
    const u64 eqA = __ballot(keyA == mnv), eqB = __ballot(keyB == mnv);
    const int ind_lowest = __builtin_ctzll(ASSEMBLE(eqA, eqB));

    // ---- per-level interval pick + secant init ----
    bool mintb[Lc], msec[Lc];
    float dinit[Lc];
    float g_dfs = 0.f, g_dbs = 0.f, g_sfs = 0.f, g_sbs = 0.f, g_dcur = 0.f, g_lr = 0.f;
    const int gl = (lane >> 3) & 3;              // secant: my level group

#pragma unroll
    for (int lv = 0; lv < Lc; ++lv) {
        const float l = lvl[lv];
        const u64 bLA = __ballot(scalA < l),  bLB = __ballot(scalB < l);
        const u64 bEA = __ballot(scalA == l), bEB = __ballot(scalB == l);
        const u64 bL = ASSEMBLE(bLA, bLB);
        const u64 bE = ASSEMBLE(bEA, bEB);
        const u64 bP = (bL >> 1) & mInt;         // scb_j < l
        const u64 bZ = (bE >> 1) & mInt;         // scb_j == l
        const u64 bI = (~bL) & (bP | bZ) & mIB;  // in-interval
        const int ind_closest = bP ? __builtin_ctzll(bP)
                                   : (bZ ? __builtin_ctzll(bZ) : (Sn - 2));
        const int idx  = bI ? ind_closest : ind_lowest;
        const int idx1 = idx + 1;

        // gather scal[idx], scal[idx+1] of my ray (2 shfl + select each)
        const int src0 = (half << 5) | (idx & 31);
        const float sfA = __shfl(scalA, src0), sfB = __shfl(scalB, src0);
        const float s_front = (idx < 32) ? sfA : sfB;
        const int src1 = (half << 5) | (idx1 & 31);
        const float sbA2 = __shfl(scalA, src1), sbB2 = __shfl(scalB, src1);
        const float s_back = (idx1 < 32) ? sbA2 : sbB2;

        // dsv is affine in idx: compute, don't gather
        const float tf = (float)idx  * (1.0f / 63.0f);
        const float d_front = d_near * (1.0f - tf) + d_far * tf;
        const float tb = (float)idx1 * (1.0f / 63.0f);
        const float d_back  = d_near * (1.0f - tb) + d_far * tb;

        const bool mi = (s_front >= l) && (l >= s_back);
        const float sd = s_front - s_back;
        const bool vd = fabsf(sd) > EPSf;
        const bool ms = mi && vd;
        const float d_sec = fastdiv((l - s_back) * d_front + (s_front - l) * d_back,
                                    vd ? sd : 1.0f);
        const float di = ms ? d_sec : d_back;

        mintb[lv] = mi; msec[lv] = ms; dinit[lv] = di;
        if (gl == lv) {
            g_dfs = d_front; g_dbs = d_back; g_sfs = s_front; g_sbs = s_back;
            g_dcur = di; g_lr = l;
        }
    }

    // ---- secant: 8 groups of 8 lanes = 2 rays x 4 levels, 8 h per lane ----
    const int sub = lane & 7;
    const float4* __restrict__ ab2 = &abq[wave][half][0];
    float4 sq[8];
#pragma unroll
    for (int j = 0; j < 8; ++j) sq[j] = ab2[sub + 8 * j];

#pragma unroll
    for (int it = 0; it < SECANT_STEPS; ++it) {
        const float mx0 = ox + g_dcur * dx, mx1 = oy + g_dcur * dy, mx2 = oz + g_dcur * dz;
        const float mn = __builtin_amdgcn_sqrtf(mx0 * mx0 + mx1 * mx1 + mx2 * mx2);
        float vv[8];
#pragma unroll
        for (int j = 0; j < 8; ++j) {
            const float y = __builtin_fmaf(g_dcur, sq[j].y, sq[j].x);
            const float e = __builtin_amdgcn_exp2f(y);
            vv[j] = __builtin_fmaf(e, sq[j].z, sq[j].z);
        }
        // 4 independent pair-rationals, balanced combine
        float tp[4];
#pragma unroll
        for (int p = 0; p < 4; ++p) {
            const float n = vv[2 * p] + vv[2 * p + 1];
            const float d = vv[2 * p] * vv[2 * p + 1];
            tp[p] = n * __builtin_amdgcn_rcpf(d);
        }
        float part = (tp[0] + tp[1]) + (tp[2] + tp[3]);
        part += DPP_XOR1(part);                  // was shfl_xor(part, 1, 16)
        part += DPP_XOR2(part);                  // was shfl_xor(part, 2, 16)
        part += __shfl_xor(part, 4, 16);         // xor4: no DPP16 encoding
        const float s_mid = (part + sbase) - mn;
        const bool mv = mn < R_SPHEREf;
        const bool upf = (s_mid > g_lr) && mv;
        const bool upb = (s_mid < g_lr) && mv;
        if (upf) { g_dfs = g_dcur; g_sfs = s_mid; }
        if (upb) { g_dbs = g_dcur; g_sbs = s_mid; }
        const float sd2 = g_sfs - g_sbs;
        const bool ok = fabsf(sd2) > EPSf;
        if (ok) g_dcur = fastdiv((g_lr - g_sbs) * g_dfs + (g_sfs - g_lr) * g_dbs, sd2);
    }

    // gather my ray's per-level results (groups at half*32 + 8*lv)
    float v0g, v1g, v2g, v3g;
    {
        const int gb = half << 5;
        const float dc0 = __shfl(g_dcur, gb);
        const float dc1 = __shfl(g_dcur, gb + 8);
        const float dc2 = __shfl(g_dcur, gb + 16);
        const float dc3 = __shfl(g_dcur, gb + 24);
        v0g = msec[0] ? dc0 : dinit[0];
        v1g = msec[1] ? dc1 : dinit[1];
        v2g = msec[2] ? dc2 : dinit[2];
        v3g = msec[3] ? dc3 : dinit[3];
    }
    int m0 = mintb[0], m1 = mintb[1], m2 = mintb[2], m3 = mintb[3];
    int i0 = 0, i1 = 1, i2 = 2, i3 = 3;

    // stable sort of 4 by (value, original index) — 5-comparator network
#define CSWAP(va, ia, ma, vb, ib, mb)                                    \
    { bool sw = (vb < va) || (vb == va && ib < ia);                      \
      if (sw) { float tv = va; va = vb; vb = tv;                         \
                int ti = ia; ia = ib; ib = ti;                           \
                int tm = ma; ma = mb; mb = tm; } }
    CSWAP(v0g, i0, m0, v1g, i1, m1);
    CSWAP(v2g, i2, m2, v3g, i3, m3);
    CSWAP(v0g, i0, m0, v2g, i2, m2);
    CSWAP(v1g, i1, m1, v3g, i3, m3);
    CSWAP(v1g, i1, m1, v2g, i2, m2);
#undef CSWAP

    const long long NL = (long long)N * Lc;
    if (sl5 < 2 * Lc && r < N) {
        const int k = sl5 & 3;
        const float dvs = (k == 0) ? v0g : (k == 1) ? v1g : (k == 2) ? v2g : v3g;
        const int   mms = (k == 0) ? m0 : (k == 1) ? m1 : (k == 2) ? m2 : m3;
        const bool isd = sl5 < Lc;
        const float val = isd ? (mask_bound ? dvs : 0.0f)
                              : ((mms && mask_bound) ? 1.0f : 0.0f);
        const long long off = (long long)r * Lc + k + (isd ? 0LL : NL);
        out[off] = val;
    }
}

extern "C" void kernel_launch(void* const* d_in, const int* in_sizes, int n_in,
                              void* d_out, int out_size, void* d_ws, size_t ws_size,
                              hipStream_t stream) {
    const float* rays_o = (const float*)d_in[0];
    const float* rays_d = (const float*)d_in[1];
    const float* levels = (const float*)d_in[2];
    const float* W1 = (const float*)d_in[3];
    const float* b1 = (const float*)d_in[4];
    const float* W2 = (const float*)d_in[5];
    const float* b2 = (const float*)d_in[6];
    float* out = (float*)d_out;

    const int N = in_sizes[0] / 3;          // B*R rays
    const int blocks = (N + 7) / 8;         // 4 waves x 2 rays per 256-thread block
    manifold_render_kernel<<<blocks, 256, 0, stream>>>(
        rays_o, rays_d, levels, W1, b1, W2, b2, out, N);
}